// Round 2
// baseline (537.932 us; speedup 1.0000x reference)
//
#include <hip/hip_runtime.h>
#include <math.h>

#define NPIX 4096
#define CIN  512
#define CR   64
#define NB   16

// workspace layout (float offsets)
static const size_t Q_OFF   = 0;                                   // [16][64][4096]
static const size_t W1T_OFF = (size_t)NB * CR * NPIX;              // [512][64]
static const size_t AP_OFF  = W1T_OFF + (size_t)CIN * CR;          // [16][32][64][64]
static const size_t ATT_OFF = AP_OFF + (size_t)NB * 32 * CR * CR;  // [16][64][64]
static const size_t MT_OFF  = ATT_OFF + (size_t)NB * CR * CR;      // [16][64][512]
// total = 6,914,048 floats = 27.7 MB

// K0: w1t[c][o] = w1[o][c]  (contiguous-in-o rows for scalar broadcast loads)
__global__ __launch_bounds__(256) void k0_w1t(const float* __restrict__ w1,
                                              float* __restrict__ w1t) {
    int idx = blockIdx.x * 256 + threadIdx.x;   // 0..32767
    int c = idx >> 6, o = idx & 63;
    w1t[idx] = w1[o * CIN + c];
}

// K1: q[b][o][n] = sum_c w1[o][c] * x[b][c][n] + b1[o]
// 1024-thread blocks: 4 c-groups x 256 pixels. Each group reduces 128 input
// channels into 64 regs; 4-way LDS tree reduce (stride-17 pad, conflict-free).
// 16 waves/block -> 4 waves/SIMD (was 1/SIMD: the round-1 latency bottleneck).
__global__ __launch_bounds__(1024) void k1_conv1(const float* __restrict__ x,
                                                 const float* __restrict__ w1t,
                                                 const float* __restrict__ b1,
                                                 float* __restrict__ q) {
    __shared__ float red[4 * 256 * 17];
    int b = blockIdx.y;
    int t = threadIdx.x;
    int px = t & 255;
    int g  = t >> 8;          // c-group 0..3
    int n = blockIdx.x * 256 + px;
    const float* xb = x + ((size_t)b * CIN + g * 128) * NPIX + n;
    const float* wb = w1t + (g * 128) * CR;
    float acc[CR];
#pragma unroll
    for (int o = 0; o < CR; o++) acc[o] = 0.f;
#pragma unroll 4
    for (int c = 0; c < 128; c++) {
        float xv = xb[(size_t)c * NPIX];
        const float* wr = wb + c * CR;
#pragma unroll
        for (int o = 0; o < CR; o++) acc[o] += wr[o] * xv;
    }
    float* qb = q + (size_t)b * CR * NPIX + n;
#pragma unroll 1
    for (int p = 0; p < 4; p++) {
        if (p) __syncthreads();
#pragma unroll
        for (int j = 0; j < 16; j++) red[(g * 256 + px) * 17 + j] = acc[p * 16 + j];
        __syncthreads();
#pragma unroll
        for (int k = 0; k < 4; k++) {
            int j = g * 4 + k;
            float s = red[(0 * 256 + px) * 17 + j] + red[(1 * 256 + px) * 17 + j]
                    + red[(2 * 256 + px) * 17 + j] + red[(3 * 256 + px) * 17 + j];
            int o = p * 16 + j;
            qb[(size_t)o * NPIX] = s + b1[o];
        }
    }
}

// K2a: per-(b, n-chunk of 128) partial att: ap[b][ch][c][d] = sum_{n in chunk} q[c][n] q[d][n]
__global__ __launch_bounds__(256) void k2a_att_part(const float* __restrict__ q,
                                                    float* __restrict__ ap) {
    __shared__ float qs[CR * 129];
    int b = blockIdx.y, ch = blockIdx.x;
    int t = threadIdx.x;
    const float* qb = q + (size_t)b * CR * NPIX + ch * 128;
#pragma unroll
    for (int i = 0; i < 32; i++) {
        int idx = i * 256 + t;
        int c = idx >> 7, n = idx & 127;
        qs[c * 129 + n] = qb[(size_t)c * NPIX + n];
    }
    __syncthreads();
    int c0 = (t & 15) * 4, d0 = (t >> 4) * 4;
    float acc[4][4];
#pragma unroll
    for (int a = 0; a < 4; a++)
#pragma unroll
        for (int e = 0; e < 4; e++) acc[a][e] = 0.f;
    for (int n = 0; n < 128; n++) {
        float rc[4], rd[4];
#pragma unroll
        for (int a = 0; a < 4; a++) rc[a] = qs[(c0 + a) * 129 + n];
#pragma unroll
        for (int e = 0; e < 4; e++) rd[e] = qs[(d0 + e) * 129 + n];
#pragma unroll
        for (int a = 0; a < 4; a++)
#pragma unroll
            for (int e = 0; e < 4; e++) acc[a][e] += rc[a] * rd[e];
    }
    float* app = ap + ((size_t)(b * 32 + ch) * CR) * CR;
#pragma unroll
    for (int a = 0; a < 4; a++)
#pragma unroll
        for (int e = 0; e < 4; e++)
            app[(c0 + a) * CR + d0 + e] = acc[a][e];
}

// K2b: att[b][c][d] = softmax_d( sum_ch ap[b][ch][c][d] )
__global__ __launch_bounds__(256) void k2b_softmax(const float* __restrict__ ap,
                                                   float* __restrict__ att) {
    int b = blockIdx.x;
    int t = threadIdx.x;
    int lane = t & 63;   // d
    int wrow = t >> 6;   // starting c (4 waves)
    for (int c = wrow; c < CR; c += 4) {
        float v = 0.f;
        for (int ch = 0; ch < 32; ch++)
            v += ap[(((size_t)(b * 32 + ch) * CR) + c) * CR + lane];
        float m = v;
#pragma unroll
        for (int s = 1; s < 64; s <<= 1) m = fmaxf(m, __shfl_xor(m, s, 64));
        float e = __expf(v - m);
        float ssum = e;
#pragma unroll
        for (int s = 1; s < 64; s <<= 1) ssum += __shfl_xor(ssum, s, 64);
        att[((size_t)b * CR + c) * CR + lane] = e / ssum;
    }
}

// K3: Mt[b][d][c] = sum_k w2[c][k] * att[b][k][d]   (fold conv-out into attention)
__global__ __launch_bounds__(256) void k3_m(const float* __restrict__ w2,
                                            const float* __restrict__ att,
                                            float* __restrict__ mt) {
    int b = blockIdx.y;
    int c = blockIdx.x * 256 + threadIdx.x;  // 0..511
    const float* ab = att + (size_t)b * CR * CR;
    const float* w2r = w2 + (size_t)c * CR;
    float acc[CR];
#pragma unroll
    for (int o = 0; o < CR; o++) acc[o] = 0.f;
    for (int k = 0; k < CR; k++) {
        float wv = w2r[k];
#pragma unroll
        for (int o = 0; o < CR; o++) acc[o] += wv * ab[k * CR + o];
    }
    float* mtb = mt + (size_t)b * CR * CIN;
#pragma unroll
    for (int o = 0; o < CR; o++) mtb[o * CIN + c] = acc[o];
}

// K4: y[b][c][n] = sum_d Mt[b][d][c] * q[b][d][n] + b2[c] + x[b][c][n]
__global__ __launch_bounds__(256) void k4_out(const float* __restrict__ q,
                                              const float* __restrict__ mt,
                                              const float* __restrict__ b2,
                                              const float* __restrict__ x,
                                              float* __restrict__ y) {
    int nt = blockIdx.x, cc = blockIdx.y, b = blockIdx.z;
    int n = nt * 256 + threadIdx.x;
    const float* qb = q + (size_t)b * CR * NPIX + n;
    const float* mtb = mt + (size_t)b * CR * CIN + cc * 64;
    float acc[64];
#pragma unroll
    for (int j = 0; j < 64; j++) acc[j] = 0.f;
#pragma unroll 2
    for (int o = 0; o < CR; o++) {
        float qv = qb[(size_t)o * NPIX];
        const float* mr = mtb + (size_t)o * CIN;
#pragma unroll
        for (int j = 0; j < 64; j++) acc[j] += qv * mr[j];
    }
    size_t base = ((size_t)b * CIN + cc * 64) * NPIX + n;
#pragma unroll
    for (int j = 0; j < 64; j++) {
        y[base + (size_t)j * NPIX] = acc[j] + b2[cc * 64 + j] + x[base + (size_t)j * NPIX];
    }
}

extern "C" void kernel_launch(void* const* d_in, const int* in_sizes, int n_in,
                              void* d_out, int out_size, void* d_ws, size_t ws_size,
                              hipStream_t stream) {
    const float* x  = (const float*)d_in[0];
    const float* w1 = (const float*)d_in[1];
    const float* b1 = (const float*)d_in[2];
    const float* w2 = (const float*)d_in[3];
    const float* b2 = (const float*)d_in[4];
    float* y  = (float*)d_out;
    float* ws = (float*)d_ws;

    float* q   = ws + Q_OFF;
    float* w1t = ws + W1T_OFF;
    float* ap  = ws + AP_OFF;
    float* att = ws + ATT_OFF;
    float* mt  = ws + MT_OFF;

    hipLaunchKernelGGL(k0_w1t,      dim3(128),        dim3(256),  0, stream, w1, w1t);
    hipLaunchKernelGGL(k1_conv1,    dim3(16, 16),     dim3(1024), 0, stream, x, w1t, b1, q);
    hipLaunchKernelGGL(k2a_att_part,dim3(32, 16),     dim3(256),  0, stream, q, ap);
    hipLaunchKernelGGL(k2b_softmax, dim3(16),         dim3(256),  0, stream, ap, att);
    hipLaunchKernelGGL(k3_m,        dim3(2, 16),      dim3(256),  0, stream, w2, att, mt);
    hipLaunchKernelGGL(k4_out,      dim3(16, 8, 16),  dim3(256),  0, stream, q, mt, b2, x, y);
}

// Round 3
// 193.588 us; speedup vs baseline: 2.7787x; 2.7787x over previous
//
#include <hip/hip_runtime.h>
#include <math.h>

#define NPIX 4096
#define CIN  512
#define CR   64
#define NB   16

// workspace layout (float offsets)
static const size_t Q_OFF   = 0;                                   // [16][64][4096]
static const size_t W1T_OFF = (size_t)NB * CR * NPIX;              // [512][64]
static const size_t AP_OFF  = W1T_OFF + (size_t)CIN * CR;          // [16][32][64][64]
static const size_t ATT_OFF = AP_OFF + (size_t)NB * 32 * CR * CR;  // [16][64][64]
static const size_t MT_OFF  = ATT_OFF + (size_t)NB * CR * CR;      // [16][64][512]
// total = 6,914,048 floats = 27.7 MB

#define F4(p) (*(const float4*)(p))

// K0: w1t[c][o] = w1[o][c]  (contiguous-in-o rows for staging)
__global__ __launch_bounds__(256) void k0_w1t(const float* __restrict__ w1,
                                              float* __restrict__ w1t) {
    int idx = blockIdx.x * 256 + threadIdx.x;   // 0..32767
    int c = idx >> 6, o = idx & 63;
    w1t[idx] = w1[o * CIN + c];
}

// K1: q[b][o][n] = sum_c w1[o][c] * x[b][c][n] + b1[o]
// Register-tiled GEMM: block = 64ch x 64px tile, thread = 4x4 regs.
// Both operands LDS-staged per 64-k chunk; 2 ds_read_b128 per 16 FMA.
__global__ __launch_bounds__(256) void k1_conv1(const float* __restrict__ x,
                                                const float* __restrict__ w1t,
                                                const float* __restrict__ b1,
                                                float* __restrict__ q) {
    __shared__ float ws[64 * 64];   // [kk][ch]
    __shared__ float xs[64 * 64];   // [kk][px]
    int b = blockIdx.y;
    int t = threadIdx.x;
    int pxg = t & 15, chg = t >> 4;
    int ch = chg * 4;
    int px0 = blockIdx.x * 64;

    float acc[4][4];
#pragma unroll
    for (int i = 0; i < 4; i++)
#pragma unroll
        for (int j = 0; j < 4; j++) acc[i][j] = 0.f;

    for (int kc = 0; kc < 8; kc++) {
        const float4* wsrc = (const float4*)(w1t + kc * 64 * 64);
        const float* xrow = x + ((size_t)b * CIN + kc * 64) * NPIX + px0;
#pragma unroll
        for (int j = 0; j < 4; j++) {
            int f = j * 256 + t;            // float4 index
            ((float4*)ws)[f] = wsrc[f];
            int kk = f >> 4, p4 = f & 15;
            ((float4*)xs)[f] = F4(xrow + (size_t)kk * NPIX + p4 * 4);
        }
        __syncthreads();
#pragma unroll 8
        for (int kk = 0; kk < 64; kk++) {
            float4 wv = F4(ws + kk * 64 + ch);
            float4 xv = F4(xs + kk * 64 + pxg * 4);
            const float* wp = (const float*)&wv;
            const float* xp = (const float*)&xv;
#pragma unroll
            for (int ci = 0; ci < 4; ci++)
#pragma unroll
                for (int pi = 0; pi < 4; pi++)
                    acc[ci][pi] = fmaf(wp[ci], xp[pi], acc[ci][pi]);
        }
        __syncthreads();
    }
    float* qb = q + (size_t)b * CR * NPIX + px0 + pxg * 4;
#pragma unroll
    for (int ci = 0; ci < 4; ci++) {
        float bb = b1[ch + ci];
        float4 o;
        o.x = acc[ci][0] + bb; o.y = acc[ci][1] + bb;
        o.z = acc[ci][2] + bb; o.w = acc[ci][3] + bb;
        *(float4*)(qb + (size_t)(ch + ci) * NPIX) = o;
    }
}

// K2a: per-(b, n-chunk of 128) partial att: ap[b][ch][c][d] = sum_{n} q[c][n] q[d][n]
__global__ __launch_bounds__(256) void k2a_att_part(const float* __restrict__ q,
                                                    float* __restrict__ ap) {
    __shared__ float qs[CR * 129];
    int b = blockIdx.y, chk = blockIdx.x;
    int t = threadIdx.x;
    const float* qb = q + (size_t)b * CR * NPIX + chk * 128;
#pragma unroll
    for (int i = 0; i < 32; i++) {
        int idx = i * 256 + t;
        int c = idx >> 7, n = idx & 127;
        qs[c * 129 + n] = qb[(size_t)c * NPIX + n];
    }
    __syncthreads();
    int c0 = (t & 15) * 4, d0 = (t >> 4) * 4;
    float acc[4][4];
#pragma unroll
    for (int a = 0; a < 4; a++)
#pragma unroll
        for (int e = 0; e < 4; e++) acc[a][e] = 0.f;
    for (int n = 0; n < 128; n++) {
        float rc[4], rd[4];
#pragma unroll
        for (int a = 0; a < 4; a++) rc[a] = qs[(c0 + a) * 129 + n];
#pragma unroll
        for (int e = 0; e < 4; e++) rd[e] = qs[(d0 + e) * 129 + n];
#pragma unroll
        for (int a = 0; a < 4; a++)
#pragma unroll
            for (int e = 0; e < 4; e++) acc[a][e] += rc[a] * rd[e];
    }
    float* app = ap + ((size_t)(b * 32 + chk) * CR) * CR;
#pragma unroll
    for (int a = 0; a < 4; a++)
#pragma unroll
        for (int e = 0; e < 4; e++)
            app[(c0 + a) * CR + d0 + e] = acc[a][e];
}

// K2b: att[b][c][d] = softmax_d( sum_ch ap[b][ch][c][d] )
__global__ __launch_bounds__(256) void k2b_softmax(const float* __restrict__ ap,
                                                   float* __restrict__ att) {
    int b = blockIdx.x;
    int t = threadIdx.x;
    int lane = t & 63;   // d
    int wrow = t >> 6;   // starting c (4 waves)
    for (int c = wrow; c < CR; c += 4) {
        float v = 0.f;
        for (int chk = 0; chk < 32; chk++)
            v += ap[(((size_t)(b * 32 + chk) * CR) + c) * CR + lane];
        float m = v;
#pragma unroll
        for (int s = 1; s < 64; s <<= 1) m = fmaxf(m, __shfl_xor(m, s, 64));
        float e = __expf(v - m);
        float ssum = e;
#pragma unroll
        for (int s = 1; s < 64; s <<= 1) ssum += __shfl_xor(ssum, s, 64);
        att[((size_t)b * CR + c) * CR + lane] = e / ssum;
    }
}

// K3: Mt[b][d][c] = sum_k w2[c][k] * att[b][k][d]   (fold conv-out into attention)
__global__ __launch_bounds__(256) void k3_m(const float* __restrict__ w2,
                                            const float* __restrict__ att,
                                            float* __restrict__ mt) {
    int b = blockIdx.y;
    int c = blockIdx.x * 256 + threadIdx.x;  // 0..511
    const float* ab = att + (size_t)b * CR * CR;
    const float* w2r = w2 + (size_t)c * CR;
    float acc[CR];
#pragma unroll
    for (int o = 0; o < CR; o++) acc[o] = 0.f;
    for (int k = 0; k < CR; k++) {
        float wv = w2r[k];
#pragma unroll
        for (int o = 0; o < CR; o++) acc[o] += wv * ab[k * CR + o];
    }
    float* mtb = mt + (size_t)b * CR * CIN;
#pragma unroll
    for (int o = 0; o < CR; o++) mtb[o * CIN + c] = acc[o];
}

// K4: y[b][c][n] = sum_d Mt[b][d][c] * q[b][d][n] + b2[c] + x[b][c][n]
// Same register-tiled GEMM shape as K1 with a single 64-k chunk (d), plus
// bias + residual epilogue.
__global__ __launch_bounds__(256) void k4_out(const float* __restrict__ q,
                                              const float* __restrict__ mt,
                                              const float* __restrict__ b2,
                                              const float* __restrict__ x,
                                              float* __restrict__ y) {
    __shared__ float ms[64 * 64];   // [d][ch]
    __shared__ float qs[64 * 64];   // [d][px]
    int nt = blockIdx.x, cc = blockIdx.y, b = blockIdx.z;
    int t = threadIdx.x;
    int pxg = t & 15, chg = t >> 4;
    int ch = chg * 4;
    int px0 = nt * 64;

#pragma unroll
    for (int j = 0; j < 4; j++) {
        int f = j * 256 + t;
        int d = f >> 4, c4 = f & 15;
        ((float4*)ms)[f] = F4(mt + ((size_t)b * CR + d) * CIN + cc * 64 + c4 * 4);
        ((float4*)qs)[f] = F4(q + ((size_t)b * CR + d) * NPIX + px0 + c4 * 4);
    }
    __syncthreads();

    float acc[4][4];
#pragma unroll
    for (int i = 0; i < 4; i++)
#pragma unroll
        for (int j = 0; j < 4; j++) acc[i][j] = 0.f;
#pragma unroll 8
    for (int d = 0; d < 64; d++) {
        float4 mv = F4(ms + d * 64 + ch);
        float4 qv = F4(qs + d * 64 + pxg * 4);
        const float* mp = (const float*)&mv;
        const float* qp = (const float*)&qv;
#pragma unroll
        for (int ci = 0; ci < 4; ci++)
#pragma unroll
            for (int pi = 0; pi < 4; pi++)
                acc[ci][pi] = fmaf(mp[ci], qp[pi], acc[ci][pi]);
    }

    size_t xbase = ((size_t)b * CIN + cc * 64 + ch) * NPIX + px0 + pxg * 4;
#pragma unroll
    for (int ci = 0; ci < 4; ci++) {
        float bb = b2[cc * 64 + ch + ci];
        float4 xv = F4(x + xbase + (size_t)ci * NPIX);
        float4 o;
        o.x = acc[ci][0] + bb + xv.x; o.y = acc[ci][1] + bb + xv.y;
        o.z = acc[ci][2] + bb + xv.z; o.w = acc[ci][3] + bb + xv.w;
        *(float4*)(y + xbase + (size_t)ci * NPIX) = o;
    }
}

extern "C" void kernel_launch(void* const* d_in, const int* in_sizes, int n_in,
                              void* d_out, int out_size, void* d_ws, size_t ws_size,
                              hipStream_t stream) {
    const float* x  = (const float*)d_in[0];
    const float* w1 = (const float*)d_in[1];
    const float* b1 = (const float*)d_in[2];
    const float* w2 = (const float*)d_in[3];
    const float* b2 = (const float*)d_in[4];
    float* y  = (float*)d_out;
    float* ws = (float*)d_ws;

    float* q   = ws + Q_OFF;
    float* w1t = ws + W1T_OFF;
    float* ap  = ws + AP_OFF;
    float* att = ws + ATT_OFF;
    float* mt  = ws + MT_OFF;

    hipLaunchKernelGGL(k0_w1t,      dim3(128),        dim3(256), 0, stream, w1, w1t);
    hipLaunchKernelGGL(k1_conv1,    dim3(64, 16),     dim3(256), 0, stream, x, w1t, b1, q);
    hipLaunchKernelGGL(k2a_att_part,dim3(32, 16),     dim3(256), 0, stream, q, ap);
    hipLaunchKernelGGL(k2b_softmax, dim3(16),         dim3(256), 0, stream, ap, att);
    hipLaunchKernelGGL(k3_m,        dim3(2, 16),      dim3(256), 0, stream, w2, att, mt);
    hipLaunchKernelGGL(k4_out,      dim3(64, 8, 16),  dim3(256), 0, stream, q, mt, b2, x, y);
}

// Round 4
// 159.628 us; speedup vs baseline: 3.3699x; 1.2127x over previous
//
#include <hip/hip_runtime.h>
#include <math.h>

#define NPIX 4096
#define CIN  512
#define CR   64
#define NB   16

// workspace layout (float offsets)
static const size_t Q_OFF   = 0;                                   // [16][64][4096]
static const size_t W1T_OFF = (size_t)NB * CR * NPIX;              // [512][64]
static const size_t AP_OFF  = W1T_OFF + (size_t)CIN * CR;          // [16][32][64][64]
static const size_t ATT_OFF = AP_OFF + (size_t)NB * 32 * CR * CR;  // [16][64][64]
static const size_t MT_OFF  = ATT_OFF + (size_t)NB * CR * CR;      // [16][64][512]
// total = 6,914,048 floats = 27.7 MB

#define F4(p) (*(const float4*)(p))

// K0: w1t[c][o] = w1[o][c]  (contiguous-in-o rows for staging)
__global__ __launch_bounds__(256) void k0_w1t(const float* __restrict__ w1,
                                              float* __restrict__ w1t) {
    int idx = blockIdx.x * 256 + threadIdx.x;   // 0..32767
    int c = idx >> 6, o = idx & 63;
    w1t[idx] = w1[o * CIN + c];
}

// K1: q[b][o][n] = sum_c w1[o][c] * x[b][c][n] + b1[o]
// Block tile 64o x 128px, thread tile 4o x 8px (32 FMA per 3 ds_read_b128).
// Padded LDS strides (132 / 68) keep reads conflict-light; KC=64 -> 8 barriers.
__global__ __launch_bounds__(256) void k1_conv1(const float* __restrict__ x,
                                                const float* __restrict__ w1t,
                                                const float* __restrict__ b1,
                                                float* __restrict__ q) {
    __shared__ float xs[64 * 132];   // [kk][px] fp32, pad 4
    __shared__ float wsm[64 * 68];   // [kk][o]  fp32, pad 4
    int b = blockIdx.y;
    int px0 = blockIdx.x * 128;
    int t = threadIdx.x;
    int pxg = t & 15;        // 8 px each
    int og  = t >> 4;        // 4 o each

    float acc[4][8];
#pragma unroll
    for (int i = 0; i < 4; i++)
#pragma unroll
        for (int j = 0; j < 8; j++) acc[i][j] = 0.f;

    for (int kc = 0; kc < 8; kc++) {
        const float* xsrc = x + ((size_t)b * CIN + kc * 64) * NPIX + px0;
        const float* wsrc = w1t + kc * 64 * 64;
#pragma unroll
        for (int j = 0; j < 8; j++) {
            int f = j * 256 + t;             // 0..2047
            int kk = f >> 5, p4 = f & 31;
            *(float4*)(xs + kk * 132 + p4 * 4) = F4(xsrc + (size_t)kk * NPIX + p4 * 4);
        }
#pragma unroll
        for (int j = 0; j < 4; j++) {
            int f = j * 256 + t;             // 0..1023
            int kk = f >> 4, o4 = f & 15;
            *(float4*)(wsm + kk * 68 + o4 * 4) = F4(wsrc + f * 4);
        }
        __syncthreads();
#pragma unroll 4
        for (int kk = 0; kk < 64; kk++) {
            float4 wv = F4(wsm + kk * 68 + og * 4);
            float4 x0 = F4(xs + kk * 132 + pxg * 8);
            float4 x1 = F4(xs + kk * 132 + pxg * 8 + 4);
            const float* wp = (const float*)&wv;
            const float* xp0 = (const float*)&x0;
            const float* xp1 = (const float*)&x1;
#pragma unroll
            for (int ci = 0; ci < 4; ci++) {
#pragma unroll
                for (int pi = 0; pi < 4; pi++) {
                    acc[ci][pi]     = fmaf(wp[ci], xp0[pi], acc[ci][pi]);
                    acc[ci][pi + 4] = fmaf(wp[ci], xp1[pi], acc[ci][pi + 4]);
                }
            }
        }
        __syncthreads();
    }
    float* qb = q + (size_t)b * CR * NPIX + px0 + pxg * 8;
#pragma unroll
    for (int ci = 0; ci < 4; ci++) {
        int o = og * 4 + ci;
        float bb = b1[o];
        float4 o0, o1;
        o0.x = acc[ci][0] + bb; o0.y = acc[ci][1] + bb;
        o0.z = acc[ci][2] + bb; o0.w = acc[ci][3] + bb;
        o1.x = acc[ci][4] + bb; o1.y = acc[ci][5] + bb;
        o1.z = acc[ci][6] + bb; o1.w = acc[ci][7] + bb;
        *(float4*)(qb + (size_t)o * NPIX)     = o0;
        *(float4*)(qb + (size_t)o * NPIX + 4) = o1;
    }
}

// K2a: per-(b, n-chunk of 128) partial att: ap[b][ch][c][d] = sum_{n} q[c][n] q[d][n]
__global__ __launch_bounds__(256) void k2a_att_part(const float* __restrict__ q,
                                                    float* __restrict__ ap) {
    __shared__ float qs[CR * 129];
    int b = blockIdx.y, chk = blockIdx.x;
    int t = threadIdx.x;
    const float* qb = q + (size_t)b * CR * NPIX + chk * 128;
#pragma unroll
    for (int i = 0; i < 32; i++) {
        int idx = i * 256 + t;
        int c = idx >> 7, n = idx & 127;
        qs[c * 129 + n] = qb[(size_t)c * NPIX + n];
    }
    __syncthreads();
    int c0 = (t & 15) * 4, d0 = (t >> 4) * 4;
    float acc[4][4];
#pragma unroll
    for (int a = 0; a < 4; a++)
#pragma unroll
        for (int e = 0; e < 4; e++) acc[a][e] = 0.f;
    for (int n = 0; n < 128; n++) {
        float rc[4], rd[4];
#pragma unroll
        for (int a = 0; a < 4; a++) rc[a] = qs[(c0 + a) * 129 + n];
#pragma unroll
        for (int e = 0; e < 4; e++) rd[e] = qs[(d0 + e) * 129 + n];
#pragma unroll
        for (int a = 0; a < 4; a++)
#pragma unroll
            for (int e = 0; e < 4; e++) acc[a][e] += rc[a] * rd[e];
    }
    float* app = ap + ((size_t)(b * 32 + chk) * CR) * CR;
#pragma unroll
    for (int a = 0; a < 4; a++)
#pragma unroll
        for (int e = 0; e < 4; e++)
            app[(c0 + a) * CR + d0 + e] = acc[a][e];
}

// K2b: att[b][c][d] = softmax_d( sum_ch ap[b][ch][c][d] )
// one wave per (b,c) row; 256 blocks.
__global__ __launch_bounds__(256) void k2b_softmax(const float* __restrict__ ap,
                                                   float* __restrict__ att) {
    int cq = blockIdx.x;      // 16
    int b  = blockIdx.y;      // 16
    int t = threadIdx.x;
    int lane = t & 63;        // d
    int c = cq * 4 + (t >> 6);
    float v = 0.f;
#pragma unroll 8
    for (int chk = 0; chk < 32; chk++)
        v += ap[(((size_t)(b * 32 + chk) * CR) + c) * CR + lane];
    float m = v;
#pragma unroll
    for (int s = 1; s < 64; s <<= 1) m = fmaxf(m, __shfl_xor(m, s, 64));
    float e = __expf(v - m);
    float ssum = e;
#pragma unroll
    for (int s = 1; s < 64; s <<= 1) ssum += __shfl_xor(ssum, s, 64);
    att[((size_t)b * CR + c) * CR + lane] = e / ssum;
}

// K3: Mt[b][d][c] = sum_k w2[c][k] * att[b][k][d]  (att[b] staged in LDS)
__global__ __launch_bounds__(256) void k3_m(const float* __restrict__ w2,
                                            const float* __restrict__ att,
                                            float* __restrict__ mt) {
    __shared__ float as_[CR * CR];   // [k][d], 16 KB
    int cc = blockIdx.x;   // 8 chunks of 64 c
    int b  = blockIdx.y;
    int t = threadIdx.x;
#pragma unroll
    for (int j = 0; j < 4; j++) {
        int f = j * 256 + t;
        *(float4*)(as_ + f * 4) = F4(att + (size_t)b * CR * CR + f * 4);
    }
    __syncthreads();
    int c  = cc * 64 + (t >> 2);
    int og = t & 3;                  // 16 o each
    const float* w2r = w2 + (size_t)c * CR;
    float acc[16];
#pragma unroll
    for (int j = 0; j < 16; j++) acc[j] = 0.f;
    for (int k = 0; k < CR; k++) {
        float wv = w2r[k];
#pragma unroll
        for (int j4 = 0; j4 < 4; j4++) {
            float4 av = F4(as_ + k * CR + og * 16 + j4 * 4);
            const float* app = (const float*)&av;
#pragma unroll
            for (int u = 0; u < 4; u++)
                acc[j4 * 4 + u] = fmaf(wv, app[u], acc[j4 * 4 + u]);
        }
    }
    float* mtb = mt + (size_t)b * CR * CIN + c;
#pragma unroll
    for (int j = 0; j < 16; j++) mtb[(size_t)(og * 16 + j) * CIN] = acc[j];
}

// K4: y[b][c][n] = sum_d Mt[b][d][c] * q[b][d][n] + b2[c] + x[b][c][n]
// Same tiled GEMM as K1 (single K=64 chunk) + bias/residual epilogue.
__global__ __launch_bounds__(256) void k4_out(const float* __restrict__ q,
                                              const float* __restrict__ mt,
                                              const float* __restrict__ b2,
                                              const float* __restrict__ x,
                                              float* __restrict__ y) {
    __shared__ float qs[64 * 132];   // [d][px]
    __shared__ float ms[64 * 68];    // [d][c]
    int nt = blockIdx.x, cc = blockIdx.y, b = blockIdx.z;
    int px0 = nt * 128;
    int t = threadIdx.x;
    int pxg = t & 15;        // 8 px each
    int og  = t >> 4;        // 4 c each

    const float* qsrc = q + (size_t)b * CR * NPIX + px0;
    const float* msrc = mt + (size_t)b * CR * CIN + cc * 64;
#pragma unroll
    for (int j = 0; j < 8; j++) {
        int f = j * 256 + t;
        int kk = f >> 5, p4 = f & 31;
        *(float4*)(qs + kk * 132 + p4 * 4) = F4(qsrc + (size_t)kk * NPIX + p4 * 4);
    }
#pragma unroll
    for (int j = 0; j < 4; j++) {
        int f = j * 256 + t;
        int kk = f >> 4, o4 = f & 15;
        *(float4*)(ms + kk * 68 + o4 * 4) = F4(msrc + (size_t)kk * CIN + o4 * 4);
    }
    __syncthreads();

    float acc[4][8];
#pragma unroll
    for (int i = 0; i < 4; i++)
#pragma unroll
        for (int j = 0; j < 8; j++) acc[i][j] = 0.f;
#pragma unroll 4
    for (int kk = 0; kk < 64; kk++) {
        float4 mv = F4(ms + kk * 68 + og * 4);
        float4 q0 = F4(qs + kk * 132 + pxg * 8);
        float4 q1 = F4(qs + kk * 132 + pxg * 8 + 4);
        const float* mp = (const float*)&mv;
        const float* qp0 = (const float*)&q0;
        const float* qp1 = (const float*)&q1;
#pragma unroll
        for (int ci = 0; ci < 4; ci++) {
#pragma unroll
            for (int pi = 0; pi < 4; pi++) {
                acc[ci][pi]     = fmaf(mp[ci], qp0[pi], acc[ci][pi]);
                acc[ci][pi + 4] = fmaf(mp[ci], qp1[pi], acc[ci][pi + 4]);
            }
        }
    }

#pragma unroll
    for (int ci = 0; ci < 4; ci++) {
        int c = cc * 64 + og * 4 + ci;
        float bb = b2[c];
        size_t base = ((size_t)b * CIN + c) * NPIX + px0 + pxg * 8;
        float4 x0 = F4(x + base), x1 = F4(x + base + 4);
        float4 o0, o1;
        o0.x = acc[ci][0] + bb + x0.x; o0.y = acc[ci][1] + bb + x0.y;
        o0.z = acc[ci][2] + bb + x0.z; o0.w = acc[ci][3] + bb + x0.w;
        o1.x = acc[ci][4] + bb + x1.x; o1.y = acc[ci][5] + bb + x1.y;
        o1.z = acc[ci][6] + bb + x1.z; o1.w = acc[ci][7] + bb + x1.w;
        *(float4*)(y + base)     = o0;
        *(float4*)(y + base + 4) = o1;
    }
}

extern "C" void kernel_launch(void* const* d_in, const int* in_sizes, int n_in,
                              void* d_out, int out_size, void* d_ws, size_t ws_size,
                              hipStream_t stream) {
    const float* x  = (const float*)d_in[0];
    const float* w1 = (const float*)d_in[1];
    const float* b1 = (const float*)d_in[2];
    const float* w2 = (const float*)d_in[3];
    const float* b2 = (const float*)d_in[4];
    float* y  = (float*)d_out;
    float* ws = (float*)d_ws;

    float* q   = ws + Q_OFF;
    float* w1t = ws + W1T_OFF;
    float* ap  = ws + AP_OFF;
    float* att = ws + ATT_OFF;
    float* mt  = ws + MT_OFF;

    hipLaunchKernelGGL(k0_w1t,      dim3(128),        dim3(256), 0, stream, w1, w1t);
    hipLaunchKernelGGL(k1_conv1,    dim3(32, 16),     dim3(256), 0, stream, x, w1t, b1, q);
    hipLaunchKernelGGL(k2a_att_part,dim3(32, 16),     dim3(256), 0, stream, q, ap);
    hipLaunchKernelGGL(k2b_softmax, dim3(16, 16),     dim3(256), 0, stream, ap, att);
    hipLaunchKernelGGL(k3_m,        dim3(8, 16),      dim3(256), 0, stream, w2, att, mt);
    hipLaunchKernelGGL(k4_out,      dim3(32, 8, 16),  dim3(256), 0, stream, q, mt, b2, x, y);
}